// Round 3
// baseline (1534.658 us; speedup 1.0000x reference)
//
#include <hip/hip_runtime.h>

// SeqAutoEncoder on MI355X.
// Structure: B=64, T=2048, D=256, H=30, G=4H=120, NOUT=5.
//   K1 gemm_pre : pre1 = seq @ enc_W1[0:256] + enc_b1   (parallel, 8 GFLOP fp32)
//   K2 scan     : 65 blocks x 1 wave. Single-wave software pipeline:
//                 iter s computes L1(s) and L2(s-1) (both consume h1(s-1)).
//                 h-state exchange via v_readlane -> SGPR (no LDS, no barriers).
//                 blocks 0..63 = encoder chains; block 64 = decoder chain.
//   K3 bcast    : dec_out[b,t] = dec_seq[t]
// ws layout: pre1 [64*2048*120] f32 (62.9 MB), then dec_seq [2048] f32.
//
// R2 post-mortem: 2-wave pipelined scan = 1090 cyc/step; barrier+LDS exchange
// +unpack movs dominated (FMA issue only 240 cyc). This version removes all
// cross-wave machinery; issue floor ~600-700 cyc/step.

#define BB 64
#define TT 2048
#define DD 256
#define HH 30
#define GG 120
#define PRE_ELEMS (64u * 2048u * 120u)

__device__ __forceinline__ float fast_exp2(float x) { return __builtin_amdgcn_exp2f(x); }
__device__ __forceinline__ float fast_rcp(float x) { return __builtin_amdgcn_rcpf(x); }
__device__ __forceinline__ float tanh_f(float x) {
  // (e^2x - 1)/(e^2x + 1); exp2 overflow -> inf -> rcp -> 0 -> +/-1, correct limits
  return 1.0f - 2.0f * fast_rcp(1.0f + fast_exp2(2.0f * 1.442695040888963f * x));
}
__device__ __forceinline__ float bcastf(float v, int l) {
  return __builtin_bit_cast(float, __builtin_amdgcn_readlane(__builtin_bit_cast(int, v), l));
}

// ---------------- K1: pre1 = seq @ Wx1 + b1 ---------------- (unchanged from R1)
__global__ __launch_bounds__(256) void gemm_pre(const float* __restrict__ A,
                                                const float* __restrict__ W,
                                                const float* __restrict__ bias,
                                                float* __restrict__ out) {
  __shared__ __align__(16) float sA[32 * 132];
  __shared__ __align__(16) float sW[32 * 120];
  const int tid = threadIdx.x;
  const int row0 = blockIdx.x * 128;
  const int tx = tid % 30;
  const int ty = tid / 30;
  const bool comp = tid < 240;
  float4 acc[16];
#pragma unroll
  for (int i = 0; i < 16; ++i) acc[i] = make_float4(0.f, 0.f, 0.f, 0.f);
  const float4* A4 = (const float4*)A;
  const float4* W4 = (const float4*)W;
  const int rload = tid >> 3;
  const int kq = tid & 7;
  for (int k0 = 0; k0 < 256; k0 += 32) {
    __syncthreads();
#pragma unroll
    for (int it = 0; it < 4; ++it) {
      int idx = tid + it * 256;
      if (idx < 960) ((float4*)sW)[idx] = W4[k0 * 30 + idx];
    }
#pragma unroll
    for (int m = 0; m < 4; ++m) {
      int rr = rload + m * 32;
      float4 v = A4[(size_t)(row0 + rr) * 64 + (k0 >> 2) + kq];
      int kk = kq * 4;
      sA[(kk + 0) * 132 + rr] = v.x;
      sA[(kk + 1) * 132 + rr] = v.y;
      sA[(kk + 2) * 132 + rr] = v.z;
      sA[(kk + 3) * 132 + rr] = v.w;
    }
    __syncthreads();
    if (comp) {
#pragma unroll 4
      for (int k = 0; k < 32; ++k) {
        const float4 w = ((const float4*)sW)[k * 30 + tx];
        const float4* a4 = (const float4*)&sA[k * 132 + ty * 16];
        float4 a0 = a4[0], a1 = a4[1], a2 = a4[2], a3 = a4[3];
        float av[16] = {a0.x, a0.y, a0.z, a0.w, a1.x, a1.y, a1.z, a1.w,
                        a2.x, a2.y, a2.z, a2.w, a3.x, a3.y, a3.z, a3.w};
#pragma unroll
        for (int i = 0; i < 16; ++i) {
          acc[i].x = fmaf(av[i], w.x, acc[i].x);
          acc[i].y = fmaf(av[i], w.y, acc[i].y);
          acc[i].z = fmaf(av[i], w.z, acc[i].z);
          acc[i].w = fmaf(av[i], w.w, acc[i].w);
        }
      }
    }
  }
  if (comp) {
    const float4 bv = ((const float4*)bias)[tx];
#pragma unroll
    for (int i = 0; i < 16; ++i) {
      int row = row0 + ty * 16 + i;
      float4 r;
      r.x = acc[i].x + bv.x;
      r.y = acc[i].y + bv.y;
      r.z = acc[i].z + bv.z;
      r.w = acc[i].w + bv.w;
      ((float4*)out)[(size_t)row * 30 + tx] = r;
    }
  }
}

// ---------------- K2: single-wave fused recurrent scan ----------------
// Lane map: lanes 0..29 own gate rows r=lane for (i, f) cols (r, 60+r);
//           lanes 32..61 own rows r=lane-32 for (j, o) cols (30+r, 90+r);
//           lanes 30,31,62,63 idle (aliased to col 0, results unused).
// Cross-gate exchange (j,o -> i,f rows) = __shfl_xor(.,32).
// h-state broadcast = v_readlane into SGPR arrays sv1/sv2.
__global__ __launch_bounds__(64, 1) void scan_kernel(
    const float* __restrict__ pre, const float* __restrict__ enc_W1,
    const float* __restrict__ enc_W2, const float* __restrict__ enc_b2,
    const float* __restrict__ enc_Wd, const float* __restrict__ enc_bd,
    const float* __restrict__ dec_W1, const float* __restrict__ dec_b1,
    const float* __restrict__ dec_W2, const float* __restrict__ dec_b2,
    float* __restrict__ out, float* __restrict__ dec_seq) {
  const int lane = threadIdx.x;
  const int blk = blockIdx.x;
  const bool isdec = (blk == BB);
  const int r = lane & 31;
  const bool jo = lane >= 32;
  const int cA = (r < 30) ? (jo ? 30 + r : r) : 0;  // i or j column; idle lanes -> col 0
  const int cB = cA + 60;                           // f or o column

  const float LOG2E = 1.442695040888963f;
  const float m1 = jo ? 2.0f * LOG2E : -LOG2E;  // p1: tanh (j) / sigm (i)
  const float A1 = jo ? -2.0f : 1.0f;
  const float B1 = jo ? 1.0f : 0.0f;
  const float fb = jo ? 0.0f : 1.0f;  // forget_bias folds into p2 = sigm(accB + fb)

  // ---- register-resident weights ----
  float w1A[30], w1B[30], w2A[60], w2B[60];
  {
    const float* W1h = isdec ? (dec_W1 + GG) : (enc_W1 + 256 * GG);
#pragma unroll
    for (int k = 0; k < 30; ++k) {
      w1A[k] = W1h[k * GG + cA];
      w1B[k] = W1h[k * GG + cB];
    }
    const float* W2 = isdec ? dec_W2 : enc_W2;
#pragma unroll
    for (int k = 0; k < 60; ++k) {
      w2A[k] = W2[k * GG + cA];
      w2B[k] = W2[k * GG + cB];
    }
  }
  const float* b2 = isdec ? dec_b2 : enc_b2;
  const float b2A = b2[cA], b2B = b2[cB];

  // L1 input term: encoder reads pre1 (bias already added by gemm_pre);
  // decoder input is zero -> constant dec_b1.
  const float* pr = pre + (size_t)blk * TT * GG;
  float pcurA, pcurB, pnxtA, pnxtB;
  if (isdec) {
    pcurA = dec_b1[cA];
    pcurB = dec_b1[cB];
    pnxtA = pcurA;
    pnxtB = pcurB;
  } else {
    pcurA = pr[cA];
    pcurB = pr[cB];
    pnxtA = pr[GG + cA];
    pnxtB = pr[GG + cB];
  }

  float sv1[30], sv2[30];
#pragma unroll
  for (int k = 0; k < 30; ++k) sv2[k] = 0.f;

  float c1 = 0.f, c2 = 0.f, h1r, h2r;

  // ---- peel: L1(0) (h1(-1)=0 -> no FMAs, numerically identical) ----
  {
    float t1 = fast_rcp(1.0f + fast_exp2(pcurA * m1));
    float p1 = fmaf(t1, A1, B1);
    float p2 = fast_rcp(1.0f + fast_exp2((pcurB + fb) * -LOG2E));
    float jv = __shfl_xor(p1, 32, 64);
    float ov = __shfl_xor(p2, 32, 64);
    c1 = p1 * jv;  // c0 = 0
    h1r = tanh_f(c1) * ov;
#pragma unroll
    for (int k = 0; k < 30; ++k) sv1[k] = bcastf(h1r, k);
    // shift prefetch queue: pcur <- pre(1), pnxt <- pre(2)
    pcurA = pnxtA;
    pcurB = pnxtB;
    if (!isdec) {
      pnxtA = pr[2 * GG + cA];
      pnxtB = pr[2 * GG + cB];
    }
  }

  // ---- main loop: iter s computes L1(s) and L2(s-1) ----
  for (int s = 1; s < TT; ++s) {
    float aA = pcurA, aB = pcurB;  // L1(s) preacts (input term + bias)
    float bA = b2A, bB = b2B;      // L2(s-1) preacts
    // prefetch pre(s+2), depth-2 (~2 iters of slack for L3/HBM latency)
    float pldA = pnxtA, pldB = pnxtB;
    if (!isdec) {
      int s2 = s + 2;
      if (s2 < TT) {
        pldA = pr[(size_t)s2 * GG + cA];
        pldB = pr[(size_t)s2 * GG + cB];
      }
    }
    // FMAs: sv1 = h1(s-1) feeds both layers; sv2 = h2(s-2) feeds L2 only.
    // L2 accumulation order (h1 rows then h2 rows, single acc) preserved exactly.
#pragma unroll
    for (int k = 0; k < 30; ++k) {
      float hk = sv1[k];
      aA = fmaf(hk, w1A[k], aA);
      aB = fmaf(hk, w1B[k], aB);
      bA = fmaf(hk, w2A[k], bA);
      bB = fmaf(hk, w2B[k], bB);
    }
#pragma unroll
    for (int k = 0; k < 30; ++k) {
      float hk = sv2[k];
      bA = fmaf(hk, w2A[30 + k], bA);
      bB = fmaf(hk, w2B[30 + k], bB);
    }
    // L1(s) tail -> h1(s)
    {
      float t1 = fast_rcp(1.0f + fast_exp2(aA * m1));
      float p1 = fmaf(t1, A1, B1);
      float p2 = fast_rcp(1.0f + fast_exp2((aB + fb) * -LOG2E));
      float jv = __shfl_xor(p1, 32, 64);
      float ov = __shfl_xor(p2, 32, 64);
      c1 = fmaf(c1, p2, p1 * jv);
      h1r = tanh_f(c1) * ov;
    }
#pragma unroll
    for (int k = 0; k < 30; ++k) sv1[k] = bcastf(h1r, k);
    // L2(s-1) tail -> h2(s-1)
    {
      float u1 = fast_rcp(1.0f + fast_exp2(bA * m1));
      float q1 = fmaf(u1, A1, B1);
      float q2 = fast_rcp(1.0f + fast_exp2((bB + fb) * -LOG2E));
      float jw = __shfl_xor(q1, 32, 64);
      float ow = __shfl_xor(q2, 32, 64);
      c2 = fmaf(c2, q2, q1 * jw);
      h2r = tanh_f(c2) * ow;
    }
    if (isdec && lane == HH - 1) dec_seq[s - 1] = h2r;
#pragma unroll
    for (int k = 0; k < 30; ++k) sv2[k] = bcastf(h2r, k);
    // rotate prefetch queue
    pcurA = pnxtA;
    pcurB = pnxtB;
    pnxtA = pldA;
    pnxtB = pldB;
  }

  // ---- epilogue: L2(TT-1) ----
  {
    float bA = b2A, bB = b2B;
#pragma unroll
    for (int k = 0; k < 30; ++k) {
      float hk = sv1[k];
      bA = fmaf(hk, w2A[k], bA);
      bB = fmaf(hk, w2B[k], bB);
    }
#pragma unroll
    for (int k = 0; k < 30; ++k) {
      float hk = sv2[k];
      bA = fmaf(hk, w2A[30 + k], bA);
      bB = fmaf(hk, w2B[30 + k], bB);
    }
    float u1 = fast_rcp(1.0f + fast_exp2(bA * m1));
    float q1 = fmaf(u1, A1, B1);
    float q2 = fast_rcp(1.0f + fast_exp2((bB + fb) * -LOG2E));
    float jw = __shfl_xor(q1, 32, 64);
    float ow = __shfl_xor(q2, 32, 64);
    c2 = fmaf(c2, q2, q1 * jw);
    h2r = tanh_f(c2) * ow;
    if (isdec) {
      if (lane == HH - 1) dec_seq[TT - 1] = h2r;
    } else {
      // latent = tanh(h2(TT-1) @ enc_Wd + enc_bd); h2 broadcast via readlane
      float a = enc_bd[lane < 5 ? lane : 0];
#pragma unroll
      for (int k = 0; k < 30; ++k)
        a = fmaf(bcastf(h2r, k), enc_Wd[k * 5 + (lane < 5 ? lane : 0)], a);
      if (lane < 5) out[BB * TT + blk * 5 + lane] = tanh_f(a);
    }
  }
}

// ---------------- K3: broadcast decoder chain to all batch rows ----------------
__global__ __launch_bounds__(256) void bcast_kernel(const float* __restrict__ dec_seq,
                                                    float* __restrict__ out) {
  int i4 = blockIdx.x * 256 + threadIdx.x;  // 32768 float4s
  ((float4*)out)[i4] = ((const float4*)dec_seq)[i4 & (TT / 4 - 1)];
}

extern "C" void kernel_launch(void* const* d_in, const int* in_sizes, int n_in,
                              void* d_out, int out_size, void* d_ws, size_t ws_size,
                              hipStream_t stream) {
  const float* seq = (const float*)d_in[0];
  const float* enc_W1 = (const float*)d_in[1];
  const float* enc_b1 = (const float*)d_in[2];
  const float* enc_W2 = (const float*)d_in[3];
  const float* enc_b2 = (const float*)d_in[4];
  const float* enc_Wd = (const float*)d_in[5];
  const float* enc_bd = (const float*)d_in[6];
  // d_in[7] dec_Wd, d_in[8] dec_bd: dead code in reference (vec2 unused)
  const float* dec_W1 = (const float*)d_in[9];
  const float* dec_b1 = (const float*)d_in[10];
  const float* dec_W2 = (const float*)d_in[11];
  const float* dec_b2 = (const float*)d_in[12];
  float* out = (float*)d_out;
  float* pre = (float*)d_ws;         // 62.9 MB
  float* dec_seq = pre + PRE_ELEMS;  // 8 KB

  gemm_pre<<<dim3(1024), dim3(256), 0, stream>>>(seq, enc_W1, enc_b1, pre);
  scan_kernel<<<dim3(65), dim3(64), 0, stream>>>(pre, enc_W1, enc_W2, enc_b2,
                                                 enc_Wd, enc_bd, dec_W1, dec_b1,
                                                 dec_W2, dec_b2, out, dec_seq);
  bcast_kernel<<<dim3(128), dim3(256), 0, stream>>>(dec_seq, out);
}